// Round 1
// baseline (476.258 us; speedup 1.0000x reference)
//
#include <hip/hip_runtime.h>

#define BATCH   8192
#define SEQ     50
#define DIM     128
#define NPROTO  16
#define NUSERS  100000
#define ROWF4   (NPROTO * DIM / 4)   // 512 float4 per prototype row-set
#define DF4     (DIM / 4)            // 32 float4 per embedding

// ---------------- Kernel 1: upd[b][d] = l2norm(sum_s(feat*mask)/max(sum_s mask,1e-6)) ----------
// 4 batch rows per block of 128 threads; 32 lanes x float4 per row.
__global__ void k_upd(const float* __restrict__ feat, const float* __restrict__ mask,
                      float* __restrict__ upd) {
    int t = threadIdx.x;
    int bb = t >> 5;          // which of 4 rows
    int l = t & 31;           // float4 index within D
    int b = blockIdx.x * 4 + bb;
    if (b >= BATCH) return;
    const float4* f4 = (const float4*)(feat + (size_t)b * SEQ * DIM);
    const float* mk = mask + (size_t)b * SEQ;
    float4 acc = {0.f, 0.f, 0.f, 0.f};
    float msum = 0.f;
    for (int s = 0; s < SEQ; ++s) {
        float m = mk[s];                      // broadcast within 32-lane group
        float4 v = f4[s * DF4 + l];
        acc.x += v.x * m; acc.y += v.y * m; acc.z += v.z * m; acc.w += v.w * m;
        msum += m;
    }
    float denom = fmaxf(msum, 1e-6f);
    float inv_d = 1.0f / denom;
    acc.x *= inv_d; acc.y *= inv_d; acc.z *= inv_d; acc.w *= inv_d;
    float sq = acc.x*acc.x + acc.y*acc.y + acc.z*acc.z + acc.w*acc.w;
    // reduce across the 32 lanes of this row-group
    for (int off = 16; off >= 1; off >>= 1)
        sq += __shfl_xor(sq, off, 32);
    float norm = sqrtf(sq);
    float inv = 1.0f / fmaxf(norm, 1e-12f);
    acc.x *= inv; acc.y *= inv; acc.z *= inv; acc.w *= inv;
    ((float4*)(upd + (size_t)b * DIM))[l] = acc;
}

// ---------------- Kernel 2: partial sums of upd over batch (deterministic, no atomics) ---------
__global__ void k_partial(const float* __restrict__ upd, float* __restrict__ part) {
    int d = threadIdx.x;      // 0..127
    int j = blockIdx.x;       // 0..127
    float acc = 0.f;
    for (int b = j; b < BATCH; b += 128)
        acc += upd[(size_t)b * DIM + d];
    part[j * DIM + d] = acc;
}

// ---------------- Kernel 3: finalize new_shared -----------------------------------------------
__global__ void k_shared(const float* __restrict__ part, const float* __restrict__ sharedP,
                         float* __restrict__ out4) {
    __shared__ float red[DIM];
    int d = threadIdx.x;      // 0..127
    float s = 0.f;
    for (int j = 0; j < 128; ++j) s += part[j * DIM + d];
    float mean = s * (1.0f / (float)BATCH);
    red[d] = mean * mean;
    __syncthreads();
    for (int off = 64; off >= 1; off >>= 1) {
        if (d < off) red[d] += red[d + off];
        __syncthreads();
    }
    float norm = sqrtf(red[0]);
    float normed = mean / fmaxf(norm, 1e-12f);
    for (int p = 0; p < NPROTO; ++p)
        out4[p * DIM + d] = 0.9f * sharedP[p * DIM + d] + 0.1f * normed;
}

// ---------------- Kernel 4: bulk float4 copy (prototypes -> new_user_prototypes) ---------------
__global__ void k_copy4(const float4* __restrict__ src, float4* __restrict__ dst, size_t n4) {
    size_t i = (size_t)blockIdx.x * blockDim.x + threadIdx.x;
    size_t stride = (size_t)gridDim.x * blockDim.x;
    for (; i < n4; i += stride) dst[i] = src[i];
}

// ---------------- Kernel 5: gather + curriculum blend + momentum blend + scatter ---------------
__global__ void k_blend(const int* __restrict__ idx, const float* __restrict__ cntArr,
                        const float4* __restrict__ userP, const float4* __restrict__ sharedP,
                        const float4* __restrict__ upd,
                        float4* __restrict__ out1, float4* __restrict__ out2,
                        float4* __restrict__ out3) {
    int b = blockIdx.x;
    int u = idx[b];
    float cnt = cntArr[u];
    float w = 1.0f / (1.0f + expf(-(cnt * 0.01f - 3.0f)));
    float m = fminf(fmaxf(0.9f + cnt * 0.001f, 0.9f), 0.99f);
    float w1 = 1.0f - w, m1 = 1.0f - m;
    const float4* up = userP + (size_t)u * ROWF4;
    const float4* ub = upd + (size_t)b * DF4;
    size_t ob = (size_t)b * ROWF4;
    size_t ou = (size_t)u * ROWF4;
    for (int i = threadIdx.x; i < ROWF4; i += 256) {
        float4 p  = up[i];
        float4 sh = sharedP[i];
        float4 ud = ub[i & (DF4 - 1)];
        float4 c, nr;
        c.x = w * p.x + w1 * sh.x;  c.y = w * p.y + w1 * sh.y;
        c.z = w * p.z + w1 * sh.z;  c.w = w * p.w + w1 * sh.w;
        nr.x = m * p.x + m1 * ud.x; nr.y = m * p.y + m1 * ud.y;
        nr.z = m * p.z + m1 * ud.z; nr.w = m * p.w + m1 * ud.w;
        out1[ob + i] = c;
        out2[ob + i] = nr;
        out3[ou + i] = nr;
    }
}

// ---------------- Kernel 6: copy interaction_count --------------------------------------------
__global__ void k_copy1(const float* __restrict__ src, float* __restrict__ dst, int n) {
    int i = blockIdx.x * blockDim.x + threadIdx.x;
    int stride = gridDim.x * blockDim.x;
    for (; i < n; i += stride) dst[i] = src[i];
}

// ---------------- Kernel 7: +1 at user_idx (unique indices -> exact & deterministic) -----------
__global__ void k_inc(const int* __restrict__ idx, float* __restrict__ out5) {
    int i = blockIdx.x * blockDim.x + threadIdx.x;
    if (i < BATCH) atomicAdd(&out5[idx[i]], 1.0f);
}

extern "C" void kernel_launch(void* const* d_in, const int* in_sizes, int n_in,
                              void* d_out, int out_size, void* d_ws, size_t ws_size,
                              hipStream_t stream) {
    const int*   user_idx = (const int*)d_in[0];
    const float* features = (const float*)d_in[1];
    const float* smask    = (const float*)d_in[2];
    const float* userP    = (const float*)d_in[3];
    const float* sharedP  = (const float*)d_in[4];
    const float* icount   = (const float*)d_in[5];

    float* out = (float*)d_out;
    const size_t n1 = (size_t)BATCH * NPROTO * DIM;      // combined
    const size_t n3 = (size_t)NUSERS * NPROTO * DIM;     // new_user_prototypes
    float* out_combined = out;                           // [B,P,D]
    float* out_newrows  = out + n1;                      // [B,P,D]
    float* out_newproto = out + 2 * n1;                  // [U,P,D]
    float* out_shared   = out + 2 * n1 + n3;             // [P,D]
    float* out_count    = out_shared + (size_t)NPROTO * DIM;  // [U]

    float* ws_upd  = (float*)d_ws;                       // [B][D] = 4 MB
    float* ws_part = ws_upd + (size_t)BATCH * DIM;       // [128][D] = 64 KB

    // 1) upd
    k_upd<<<BATCH / 4, 128, 0, stream>>>(features, smask, ws_upd);
    // 2-3) shared update (deterministic two-stage mean)
    k_partial<<<128, 128, 0, stream>>>(ws_upd, ws_part);
    k_shared<<<1, 128, 0, stream>>>(ws_part, sharedP, out_shared);
    // 4) bulk copy of prototypes
    k_copy4<<<4096, 256, 0, stream>>>((const float4*)userP, (float4*)out_newproto, n3 / 4);
    // 5) gather/blend/scatter (after copy on same stream)
    k_blend<<<BATCH, 256, 0, stream>>>(user_idx, icount, (const float4*)userP,
                                       (const float4*)sharedP, (const float4*)ws_upd,
                                       (float4*)out_combined, (float4*)out_newrows,
                                       (float4*)out_newproto);
    // 6-7) interaction counts
    k_copy1<<<(NUSERS + 255) / 256, 256, 0, stream>>>(icount, out_count, NUSERS);
    k_inc<<<(BATCH + 255) / 256, 256, 0, stream>>>(user_idx, out_count);
}

// Round 3
// 355.910 us; speedup vs baseline: 1.3381x; 1.3381x over previous
//
#include <hip/hip_runtime.h>

#define BATCH   8192
#define SEQ     50
#define DIM     128
#define NPROTO  16
#define NUSERS  100000
#define ROWF4   (NPROTO * DIM / 4)   // 512 vf4 per prototype row-set
#define DF4     (DIM / 4)            // 32 vf4 per embedding

typedef float vf4 __attribute__((ext_vector_type(4)));

// ---------------- Kernel A: inv[u] = -1 ---------------------------------------------------------
__global__ void k_fill_inv(int* __restrict__ inv) {
    int i = blockIdx.x * blockDim.x + threadIdx.x;
    if (i < NUSERS) inv[i] = -1;
}

// ---------------- Kernel B: scatter batch index + per-batch blend coefficients ------------------
__global__ void k_prep(const int* __restrict__ idx, const float* __restrict__ icount,
                       int* __restrict__ inv, float2* __restrict__ wm) {
    int b = blockIdx.x * blockDim.x + threadIdx.x;
    if (b >= BATCH) return;
    int u = idx[b];
    inv[u] = b;
    float cnt = icount[u];
    float w = 1.0f / (1.0f + expf(3.0f - cnt * 0.01f));           // sigmoid(cnt/100 - 3)
    float m = fminf(fmaxf(0.9f + cnt * 0.001f, 0.9f), 0.99f);
    wm[b] = make_float2(w, m);
}

// ---------------- Kernel C: upd[b][d] = l2norm(sum_s(feat*mask)/max(sum_s mask,1e-6)) -----------
// 4 rows per 128-thread block; 32 lanes x vf4 per row.
__global__ void k_upd(const float* __restrict__ feat, const float* __restrict__ mask,
                      float* __restrict__ upd) {
    int t = threadIdx.x;
    int bb = t >> 5;
    int l = t & 31;
    int b = blockIdx.x * 4 + bb;
    const vf4* f4p = (const vf4*)(feat + (size_t)b * SEQ * DIM);
    const float* mk = mask + (size_t)b * SEQ;
    vf4 acc = {0.f, 0.f, 0.f, 0.f};
    float msum = 0.f;
    #pragma unroll 5
    for (int s = 0; s < SEQ; ++s) {
        float m = mk[s];
        vf4 v = __builtin_nontemporal_load(&f4p[s * DF4 + l]);
        acc += v * m;
        msum += m;
    }
    float inv_d = 1.0f / fmaxf(msum, 1e-6f);
    acc *= inv_d;
    float sq = acc.x*acc.x + acc.y*acc.y + acc.z*acc.z + acc.w*acc.w;
    for (int off = 16; off >= 1; off >>= 1)
        sq += __shfl_xor(sq, off, 32);
    float inv = 1.0f / fmaxf(sqrtf(sq), 1e-12f);
    acc *= inv;
    ((vf4*)(upd + (size_t)b * DIM))[l] = acc;
}

// ---------------- Kernel D: partial sums of upd over batch (deterministic) ----------------------
__global__ void k_partial(const float* __restrict__ upd, float* __restrict__ part) {
    int d = threadIdx.x;      // 0..127
    int j = blockIdx.x;       // 0..127
    float acc = 0.f;
    for (int b = j; b < BATCH; b += 128)
        acc += upd[(size_t)b * DIM + d];
    part[j * DIM + d] = acc;
}

// ---------------- Kernel E: finalize new_shared -------------------------------------------------
__global__ void k_shared(const float* __restrict__ part, const float* __restrict__ sharedP,
                         float* __restrict__ out4) {
    __shared__ float red[DIM];
    int d = threadIdx.x;      // 0..127
    float s = 0.f;
    for (int j = 0; j < 128; ++j) s += part[j * DIM + d];
    float mean = s * (1.0f / (float)BATCH);
    red[d] = mean * mean;
    __syncthreads();
    for (int off = 64; off >= 1; off >>= 1) {
        if (d < off) red[d] += red[d + off];
        __syncthreads();
    }
    float normed = mean / fmaxf(sqrtf(red[0]), 1e-12f);
    for (int p = 0; p < NPROTO; ++p)
        out4[p * DIM + d] = 0.9f * sharedP[p * DIM + d] + 0.1f * normed;
}

// ---------------- Kernel F: mega — copy OR blend per prototype row ------------------------------
// One block per user row. Non-batch rows: straight nontemporal copy.
// Batch rows: read once, emit combined (out1), new_rows (out2), scatter (out3).
__global__ void __launch_bounds__(256) k_mega(
        const int* __restrict__ inv, const float2* __restrict__ wm,
        const vf4* __restrict__ userP, const vf4* __restrict__ sharedP,
        const vf4* __restrict__ upd,
        vf4* __restrict__ out1, vf4* __restrict__ out2, vf4* __restrict__ out3) {
    int u = blockIdx.x;
    int b = inv[u];
    size_t base = (size_t)u * ROWF4;
    if (b < 0) {
        #pragma unroll
        for (int k = 0; k < 2; ++k) {
            int i = threadIdx.x + k * 256;
            vf4 v = __builtin_nontemporal_load(&userP[base + i]);
            __builtin_nontemporal_store(v, &out3[base + i]);
        }
    } else {
        float2 c2 = wm[b];
        float w = c2.x, m = c2.y;
        float w1 = 1.0f - w, m1 = 1.0f - m;
        size_t ob = (size_t)b * ROWF4;
        const vf4* ub = upd + (size_t)b * DF4;
        #pragma unroll
        for (int k = 0; k < 2; ++k) {
            int i = threadIdx.x + k * 256;
            vf4 p  = __builtin_nontemporal_load(&userP[base + i]);
            vf4 sh = sharedP[i];
            vf4 ud = ub[i & (DF4 - 1)];
            vf4 c  = w * p + w1 * sh;
            vf4 nr = m * p + m1 * ud;
            __builtin_nontemporal_store(c,  &out1[ob + i]);
            __builtin_nontemporal_store(nr, &out2[ob + i]);
            __builtin_nontemporal_store(nr, &out3[base + i]);
        }
    }
}

// ---------------- Kernel G: copy interaction_count ----------------------------------------------
__global__ void k_copy1(const float* __restrict__ src, float* __restrict__ dst, int n) {
    int i = blockIdx.x * blockDim.x + threadIdx.x;
    if (i < n) dst[i] = src[i];
}

// ---------------- Kernel H: +1 at user_idx (handles duplicate indices exactly) ------------------
__global__ void k_inc(const int* __restrict__ idx, float* __restrict__ out5) {
    int i = blockIdx.x * blockDim.x + threadIdx.x;
    if (i < BATCH) atomicAdd(&out5[idx[i]], 1.0f);
}

extern "C" void kernel_launch(void* const* d_in, const int* in_sizes, int n_in,
                              void* d_out, int out_size, void* d_ws, size_t ws_size,
                              hipStream_t stream) {
    const int*   user_idx = (const int*)d_in[0];
    const float* features = (const float*)d_in[1];
    const float* smask    = (const float*)d_in[2];
    const float* userP    = (const float*)d_in[3];
    const float* sharedP  = (const float*)d_in[4];
    const float* icount   = (const float*)d_in[5];

    float* out = (float*)d_out;
    const size_t n1 = (size_t)BATCH * NPROTO * DIM;
    const size_t n3 = (size_t)NUSERS * NPROTO * DIM;
    float* out_combined = out;
    float* out_newrows  = out + n1;
    float* out_newproto = out + 2 * n1;
    float* out_shared   = out + 2 * n1 + n3;
    float* out_count    = out_shared + (size_t)NPROTO * DIM;

    float*  ws_upd  = (float*)d_ws;                          // [B][D]   4 MB
    float*  ws_part = ws_upd + (size_t)BATCH * DIM;          // [128][D] 64 KB
    int*    ws_inv  = (int*)(ws_part + 128 * DIM);           // [U]      400 KB
    float2* ws_wm   = (float2*)(ws_inv + NUSERS);            // [B]      64 KB

    k_fill_inv<<<(NUSERS + 255) / 256, 256, 0, stream>>>(ws_inv);
    k_prep<<<(BATCH + 255) / 256, 256, 0, stream>>>(user_idx, icount, ws_inv, ws_wm);
    k_upd<<<BATCH / 4, 128, 0, stream>>>(features, smask, ws_upd);
    k_partial<<<128, 128, 0, stream>>>(ws_upd, ws_part);
    k_shared<<<1, 128, 0, stream>>>(ws_part, sharedP, out_shared);
    k_mega<<<NUSERS, 256, 0, stream>>>(ws_inv, ws_wm, (const vf4*)userP,
                                       (const vf4*)sharedP, (const vf4*)ws_upd,
                                       (vf4*)out_combined, (vf4*)out_newrows,
                                       (vf4*)out_newproto);
    k_copy1<<<(NUSERS + 255) / 256, 256, 0, stream>>>(icount, out_count, NUSERS);
    k_inc<<<(BATCH + 255) / 256, 256, 0, stream>>>(user_idx, out_count);
}